// Round 22
// baseline (309.418 us; speedup 1.0000x reference)
//
#include <hip/hip_runtime.h>

#define ALPHA 0.2f
#define NT 1000
#define NRELC 200
#define NE 500000
#define N_ENT 100000
#define CH 2048
#define G 245            // ceil(NE/CH)

// ---------------- int workspace layout (int offsets) ----------------
static constexpr size_t I_STARTS_SRC = 0;        // 1001
static constexpr size_t I_STARTS_DST = 1001;     // 1001
static constexpr size_t I_COLSUM     = 2002;     // 2000 [side][bin]
static constexpr size_t I_HIST2      = 4002;     // 2*G*NT = 490000  [side][blk][bin]
static constexpr size_t I_BASE2      = 494002;   // 490000           [side][blk][bin]
static constexpr size_t I_AB_SRC     = 984002;   // 1000000 (500000 int2: j, oth|rel<<16)
static constexpr size_t I_AB_DST     = 1984002;  // 1000000

// ---------------- float workspace layout (float offsets) ----------------
static constexpr size_t F_SC_S = 2984004;            // 500000 float2 sorted scores (src side)
static constexpr size_t F_SC_D = F_SC_S + 1000000;   // 500000 float2 sorted scores (dst side)
static constexpr size_t F_R2S  = F_SC_D + 1000000;   // 500000 float2 edge r-dots (src combos)
static constexpr size_t F_R2D  = F_R2S + 1000000;    // 500000 float2 edge r-dots (dst combos)
static constexpr size_t F_U1 = F_R2D + 1000000;      // 4 combos x 3 parts x 64
static constexpr size_t F_U2 = F_U1 + 768;           // 2 combos x 3 parts x 128
static constexpr size_t F_L1 = F_U2 + 768;           // 4 combos x 130000
//   per-combo: P1 @0 (1000x64), P2 @64000 (1000x64), C1 @128000 (1000), C2 @129000 (1000)
static constexpr size_t F_X1 = F_L1 + 4*130000;      // 1000x128
static constexpr size_t F_X2 = F_X1 + 128000;        // 1000x128
static constexpr size_t F_OR = F_X2 + 128000;        // 200x128
static constexpr size_t F_L2 = F_OR + 25600;         // 2 combos x 283800
//   per-combo: Q1 @0 (1000x128), Q2 @128000, R3 @256000 (200x128),
//              C1 @281600 (1000), C2 @282600 (1000), C3 @283600 (200)
static constexpr size_t S2F = 283800;
static constexpr size_t WS_FLOATS = F_L2 + 2*S2F;    // ~8.35M floats = 33.4MB

// ---------------- output layout (floats) ----------------
static constexpr size_t OUT_O2  = 12800000;   // 100000*128
static constexpr size_t OUT_REL = 12928000;   // + 200*128

__device__ __forceinline__ float eluf(float x) { return x > 0.f ? x : expm1f(x); }
__device__ __forceinline__ float scoref(float slin) {
  return expf(slin > 0.f ? -slin : -ALPHA * slin);
}

// ================= sort phase 1: per-chunk histograms =================
__global__ __launch_bounds__(256) void k_hist2(const int* __restrict__ src,
                                               const int* __restrict__ dst,
                                               int* __restrict__ ip) {
  __shared__ int h[NT];
  int bid = blockIdx.x;
  int side = bid >= G;
  int blk = bid - side * G;
  const int* keys = side ? dst : src;
  int j0 = blk * CH;
  int n = min(CH, NE - j0);
  for (int i = threadIdx.x; i < NT; i += 256) h[i] = 0;
  __syncthreads();
  for (int k = threadIdx.x; k < n; k += 256) atomicAdd(&h[keys[j0 + k]], 1);
  __syncthreads();
  int* row = ip + I_HIST2 + (size_t)(side * G + blk) * NT;
  for (int b = threadIdx.x; b < NT; b += 256) row[b] = h[b];
}

// ================= sort phase 2a: column sums (parallel) =================
__global__ void k_colsum(int* __restrict__ ip) {
  int t = blockIdx.x * 256 + threadIdx.x;
  if (t >= 2 * NT) return;
  int side = t / NT, bin = t - side * NT;
  int s = 0;
  for (int blk = 0; blk < G; ++blk)
    s += ip[I_HIST2 + (size_t)(side * G + blk) * NT + bin];
  ip[I_COLSUM + t] = s;
}

// ================= sort phase 2b: prefix over 1000 bins =================
__global__ void k_scan2b(int* __restrict__ ip) {
  __shared__ int buf[1024];
  int t = threadIdx.x;
  for (int side = 0; side < 2; ++side) {
    int v = (t < NT) ? ip[I_COLSUM + side * NT + t] : 0;
    buf[t] = v;
    __syncthreads();
    for (int off = 1; off < 1024; off <<= 1) {
      int x = (t >= off) ? buf[t - off] : 0;
      __syncthreads();
      buf[t] += x;
      __syncthreads();
    }
    int* st = ip + (side ? I_STARTS_DST : I_STARTS_SRC);
    if (t < NT) st[t] = buf[t] - v;
    if (t == NT - 1) st[NT] = buf[t];
    __syncthreads();
  }
}

// ================= sort phase 2c: per-(blk,bin) bases (parallel) ========
__global__ void k_bases(int* __restrict__ ip) {
  int t = blockIdx.x * 256 + threadIdx.x;
  if (t >= 2 * NT) return;
  int side = t / NT, bin = t - side * NT;
  int run = ip[(side ? I_STARTS_DST : I_STARTS_SRC) + bin];
  for (int blk = 0; blk < G; ++blk) {
    size_t idx = I_HIST2 + (size_t)(side * G + blk) * NT + bin;
    int c = ip[idx];
    ip[idx + (I_BASE2 - I_HIST2)] = run;
    run += c;
  }
}

// ================= score-factorization u-vectors =================
__global__ void k_prep_u(const float* aE0, const float* vE0, const float* aT0, const float* vT0,
                         const float* aE1, const float* vE1, const float* aT1, const float* vT1,
                         const float* aEo, const float* vEo, const float* aTo, const float* vTo,
                         float* ws) {
  int t = blockIdx.x * blockDim.x + threadIdx.x;
  if (t < 768) {
    int c = t / 192, rem = t - c*192;
    int p = rem >> 6, k = rem & 63;
    const float* a = (c==0)?aE0:(c==1)?aT0:(c==2)?aE1:aT1;
    const float* v = (c==0)?vE0:(c==1)?vT0:(c==2)?vE1:vT1;
    float s = 0.f;
    for (int o = 0; o < 64; ++o) s += a[o*192 + p*64 + k] * v[o];
    ws[F_U1 + (size_t)(c*3+p)*64 + k] = s;
  } else if (t < 1536) {
    int tt = t - 768;
    int c = tt / 384, rem = tt - c*384;
    int p = rem >> 7, k = rem & 127;
    const float* a = c ? aTo : aEo;
    const float* v = c ? vTo : vEo;
    float s = 0.f;
    for (int o = 0; o < 128; ++o) s += a[o*384 + p*128 + k] * v[o];
    ws[F_U2 + (size_t)(c*3+p)*128 + k] = s;
  }
}

// ================= layer-1 projections: LDS-tiled GEMM + C tail =============
__global__ __launch_bounds__(256) void k_l1_proj(const float* Ent, const float* Typ,
                                                 const float* aE0, const float* aT0,
                                                 const float* aE1, const float* aT1,
                                                 float* ws) {
  int bid = blockIdx.x;
  int t = threadIdx.x;
  if (bid < 504) {
    __shared__ float xs[16][64];
    int c = bid / 126, rem = bid - c*126;
    int table = rem / 63, tile = rem - table*63;
    int i0 = tile * 16;
    const float* a = (c==0)?aE0:(c==1)?aT0:(c==2)?aE1:aT1;
    const float* x = table ? Typ : Ent;
    float* outb = ws + F_L1 + (size_t)c*130000 + (table ? 64000 : 0);
    for (int idx = t; idx < 1024; idx += 256) {
      int r = idx >> 6, k = idx & 63;
      int i = i0 + r;
      xs[r][k] = (i < NT) ? x[(size_t)i*64 + k] : 0.f;
    }
    __syncthreads();
    int o = t & 63, grp = t >> 6;          // 4 groups x 4 rows
    const float* arow = a + o*192 + table*64;
    float acc0 = 0.f, acc1 = 0.f, acc2 = 0.f, acc3 = 0.f;
    #pragma unroll 8
    for (int k = 0; k < 64; ++k) {
      float av = arow[k];
      acc0 += xs[grp*4+0][k] * av;
      acc1 += xs[grp*4+1][k] * av;
      acc2 += xs[grp*4+2][k] * av;
      acc3 += xs[grp*4+3][k] * av;
    }
    int ib = i0 + grp*4;
    if (ib + 0 < NT) outb[(size_t)(ib+0)*64 + o] = acc0;
    if (ib + 1 < NT) outb[(size_t)(ib+1)*64 + o] = acc1;
    if (ib + 2 < NT) outb[(size_t)(ib+2)*64 + o] = acc2;
    if (ib + 3 < NT) outb[(size_t)(ib+3)*64 + o] = acc3;
  } else {
    int idx = (bid - 504) * 256 + t;       // 8000 = 4 combos x (C1 1000 + C2 1000)
    if (idx >= 8000) return;
    int c = idx / 2000, rem = idx - c*2000;
    float* base = ws + F_L1 + (size_t)c * 130000;
    if (rem < 1000) {
      const float* x = Ent + (size_t)rem*64;
      const float* u = ws + F_U1 + (size_t)(c*3)*64;
      float s = 0.f;
      #pragma unroll
      for (int k = 0; k < 64; ++k) s += x[k]*u[k];
      base[128000 + rem] = s;
    } else {
      int i = rem - 1000;
      const float* x = Typ + (size_t)i*64;
      const float* u = ws + F_U1 + (size_t)(c*3+1)*64;
      float s = 0.f;
      #pragma unroll
      for (int k = 0; k < 64; ++k) s += x[k]*u[k];
      base[129000 + i] = s;
    }
  }
}

// ================= sort phase 3: fused r-dots + scatter + finished scores ====
// Runs AFTER k_prep_u + k_l1_proj.
// Phase A: stream the chunk's CONTIGUOUS Eemb rows, compute this side's two
//          r-dots, write R2[j] (global, L2-resident for this block).
// Output loop: finish scores (L1-resident tables + R2) and write
//          ab int2 (j, oth|rel<<16) + sc float2 (sA, sB) at sorted positions.
__global__ __launch_bounds__(256) void k_binscat(const float* __restrict__ Eemb,
                                                 const int* __restrict__ src,
                                                 const int* __restrict__ dst,
                                                 const int* __restrict__ et,
                                                 int* __restrict__ ip,
                                                 float* __restrict__ ws) {
  __shared__ int2 bufs[CH];
  __shared__ int loff[1024];
  __shared__ int lcur[1024];
  __shared__ int gbase[1024];
  __shared__ int psum[256];
  int bid = blockIdx.x;
  int side = bid >= G;
  int blk = bid - side * G;
  const int* keys = side ? dst : src;
  const int* oths = side ? src : dst;
  int j0 = blk * CH;
  int n = min(CH, NE - j0);
  int t = threadIdx.x;

  for (int i = t; i < 1024; i += 256) lcur[i] = 0;
  __syncthreads();
  for (int k = t; k < n; k += 256) atomicAdd(&lcur[keys[j0 + k]], 1);
  __syncthreads();
  int c0 = lcur[4*t], c1 = lcur[4*t+1], c2 = lcur[4*t+2], c3 = lcur[4*t+3];
  int s = c0 + c1 + c2 + c3;
  psum[t] = s;
  __syncthreads();
  for (int off = 1; off < 256; off <<= 1) {
    int x = (t >= off) ? psum[t - off] : 0;
    __syncthreads();
    psum[t] += x;
    __syncthreads();
  }
  int base = psum[t] - s;
  loff[4*t]   = base;
  loff[4*t+1] = base + c0;
  loff[4*t+2] = base + c0 + c1;
  loff[4*t+3] = base + c0 + c1 + c2;
  lcur[4*t]   = loff[4*t];
  lcur[4*t+1] = loff[4*t+1];
  lcur[4*t+2] = loff[4*t+2];
  lcur[4*t+3] = loff[4*t+3];
  const int* brow = ip + I_BASE2 + (size_t)(side * G + blk) * NT;
  for (int b = t; b < NT; b += 256) gbase[b] = brow[b];

  // ---- phase A: contiguous Eemb stream -> R2[j] (this side's 2 combos) ----
  {
    int sub = t & 15, slot = t >> 4;
    int cA = side, cB = side + 2;
    float4 wA = reinterpret_cast<const float4*>(ws + F_U1 + (size_t)(cA*3+2)*64)[sub];
    float4 wB = reinterpret_cast<const float4*>(ws + F_U1 + (size_t)(cB*3+2)*64)[sub];
    float2* R2 = reinterpret_cast<float2*>(ws + (side ? F_R2D : F_R2S));
    const float4* EV = reinterpret_cast<const float4*>(Eemb);
    for (int k = slot; k < n; k += 16) {
      int j = j0 + k;
      float4 ev = EV[(size_t)j*16 + sub];
      float rA = ev.x*wA.x + ev.y*wA.y + ev.z*wA.z + ev.w*wA.w;
      float rB = ev.x*wB.x + ev.y*wB.y + ev.z*wB.z + ev.w*wB.w;
      #pragma unroll
      for (int sh = 1; sh < 16; sh <<= 1) {
        rA += __shfl_xor(rA, sh, 16);
        rB += __shfl_xor(rB, sh, 16);
      }
      if (sub == 0) R2[j] = make_float2(rA, rB);
    }
  }
  __syncthreads();
  for (int k = t; k < n; k += 256) {
    int j = j0 + k;
    int b = keys[j];
    int pos = atomicAdd(&lcur[b], 1);
    bufs[pos] = make_int2(j | (b << 19), oths[j] | (et[j] << 16));
  }
  __syncthreads();   // also makes phase-A R2 writes visible block-wide
  size_t ownOff = side ? 129000 : 128000;   // own-side coef (indexed by bin/key)
  size_t othOff = side ? 128000 : 129000;   // other-side coef (indexed by oth)
  const float* ownA = ws + F_L1 + (size_t)(side    )*130000 + ownOff;
  const float* ownB = ws + F_L1 + (size_t)(side + 2)*130000 + ownOff;
  const float* othA = ws + F_L1 + (size_t)(side    )*130000 + othOff;
  const float* othB = ws + F_L1 + (size_t)(side + 2)*130000 + othOff;
  const float2* R2 = reinterpret_cast<const float2*>(ws + (side ? F_R2D : F_R2S));
  int2* outAB = reinterpret_cast<int2*>(ip + (side ? I_AB_DST : I_AB_SRC));
  float2* outSC = reinterpret_cast<float2*>(ws + (side ? F_SC_D : F_SC_S));
  for (int k = t; k < n; k += 256) {
    int2 q = bufs[k];
    int b = q.x >> 19;
    int posg = gbase[b] + (k - loff[b]);
    int j = q.x & 0x7FFFF;
    int oth = q.y & 0xFFFF;
    float2 r = R2[j];
    float sA = scoref(ownA[b] + othA[oth] + r.x);
    float sB = scoref(ownB[b] + othB[oth] + r.y);
    outAB[posg] = make_int2(j, q.y);
    outSC[posg] = make_float2(sA, sB);
  }
}

// ================= layer-1: pure gather-accumulate + fused post ==============
// grid 2000, 256 threads. 8-deep unroll; scores coalesced; no shfl, no exp.
__global__ __launch_bounds__(256) void k_l1_acc(const float* __restrict__ Eemb,
                                                const float* aE0, const float* aT0,
                                                const float* aE1, const float* aT1,
                                                const int* __restrict__ ip,
                                                float* __restrict__ ws) {
  __shared__ float smem[3154];
  float* TlB   = smem;          // Tl[2][1000]
  float* accRf = smem + 2000;   // accR[16][64] (per combo) / red alias
  float* accEf = smem + 3024;   // accE[2][64]
  float* denf  = smem + 3152;   // denl[2]
  float* redf  = smem + 2000;

  int side = blockIdx.x >= NT;
  int g = blockIdx.x - side * NT;
  int t = threadIdx.x;
  int sub = t & 15, slot = t >> 4;

  for (int i = t; i < NT; i += 256) { TlB[i] = 0.f; TlB[1000 + i] = 0.f; }
  if (t < 2) denf[t] = 0.f;
  __syncthreads();

  int start = ip[(side ? I_STARTS_DST : I_STARTS_SRC) + g];
  int end   = ip[(side ? I_STARTS_DST : I_STARTS_SRC) + g + 1];
  const int2* ab = reinterpret_cast<const int2*>(ip + (side ? I_AB_DST : I_AB_SRC));
  const float2* sc = reinterpret_cast<const float2*>(ws + (side ? F_SC_D : F_SC_S));
  const float4* EV = reinterpret_cast<const float4*>(Eemb);

  float4 acc0 = make_float4(0.f,0.f,0.f,0.f);
  float4 acc1 = make_float4(0.f,0.f,0.f,0.f);
  float d0 = 0.f, d1 = 0.f;

  int p = start + slot;
  // 8-deep unrolled: 8 records + 8 scores + 8 gathers in flight
  for (; p + 112 < end; p += 128) {
    int2 q0 = ab[p], q1 = ab[p+16], q2 = ab[p+32], q3 = ab[p+48];
    int2 q4 = ab[p+64], q5 = ab[p+80], q6 = ab[p+96], q7 = ab[p+112];
    float2 s0 = sc[p], s1 = sc[p+16], s2 = sc[p+32], s3 = sc[p+48];
    float2 s4 = sc[p+64], s5 = sc[p+80], s6 = sc[p+96], s7 = sc[p+112];
    float4 e0 = EV[(size_t)q0.x*16 + sub];
    float4 e1 = EV[(size_t)q1.x*16 + sub];
    float4 e2 = EV[(size_t)q2.x*16 + sub];
    float4 e3 = EV[(size_t)q3.x*16 + sub];
    float4 e4 = EV[(size_t)q4.x*16 + sub];
    float4 e5 = EV[(size_t)q5.x*16 + sub];
    float4 e6 = EV[(size_t)q6.x*16 + sub];
    float4 e7 = EV[(size_t)q7.x*16 + sub];
    acc0.x += s0.x*e0.x + s1.x*e1.x + s2.x*e2.x + s3.x*e3.x
            + s4.x*e4.x + s5.x*e5.x + s6.x*e6.x + s7.x*e7.x;
    acc0.y += s0.x*e0.y + s1.x*e1.y + s2.x*e2.y + s3.x*e3.y
            + s4.x*e4.y + s5.x*e5.y + s6.x*e6.y + s7.x*e7.y;
    acc0.z += s0.x*e0.z + s1.x*e1.z + s2.x*e2.z + s3.x*e3.z
            + s4.x*e4.z + s5.x*e5.z + s6.x*e6.z + s7.x*e7.z;
    acc0.w += s0.x*e0.w + s1.x*e1.w + s2.x*e2.w + s3.x*e3.w
            + s4.x*e4.w + s5.x*e5.w + s6.x*e6.w + s7.x*e7.w;
    acc1.x += s0.y*e0.x + s1.y*e1.x + s2.y*e2.x + s3.y*e3.x
            + s4.y*e4.x + s5.y*e5.x + s6.y*e6.x + s7.y*e7.x;
    acc1.y += s0.y*e0.y + s1.y*e1.y + s2.y*e2.y + s3.y*e3.y
            + s4.y*e4.y + s5.y*e5.y + s6.y*e6.y + s7.y*e7.y;
    acc1.z += s0.y*e0.z + s1.y*e1.z + s2.y*e2.z + s3.y*e3.z
            + s4.y*e4.z + s5.y*e5.z + s6.y*e6.z + s7.y*e7.z;
    acc1.w += s0.y*e0.w + s1.y*e1.w + s2.y*e2.w + s3.y*e3.w
            + s4.y*e4.w + s5.y*e5.w + s6.y*e6.w + s7.y*e7.w;
    if (sub == 0) {
      atomicAdd(&TlB[q0.y & 0xFFFF], s0.x); atomicAdd(&TlB[1000+(q0.y & 0xFFFF)], s0.y);
      atomicAdd(&TlB[q1.y & 0xFFFF], s1.x); atomicAdd(&TlB[1000+(q1.y & 0xFFFF)], s1.y);
      atomicAdd(&TlB[q2.y & 0xFFFF], s2.x); atomicAdd(&TlB[1000+(q2.y & 0xFFFF)], s2.y);
      atomicAdd(&TlB[q3.y & 0xFFFF], s3.x); atomicAdd(&TlB[1000+(q3.y & 0xFFFF)], s3.y);
      atomicAdd(&TlB[q4.y & 0xFFFF], s4.x); atomicAdd(&TlB[1000+(q4.y & 0xFFFF)], s4.y);
      atomicAdd(&TlB[q5.y & 0xFFFF], s5.x); atomicAdd(&TlB[1000+(q5.y & 0xFFFF)], s5.y);
      atomicAdd(&TlB[q6.y & 0xFFFF], s6.x); atomicAdd(&TlB[1000+(q6.y & 0xFFFF)], s6.y);
      atomicAdd(&TlB[q7.y & 0xFFFF], s7.x); atomicAdd(&TlB[1000+(q7.y & 0xFFFF)], s7.y);
      d0 += s0.x + s1.x + s2.x + s3.x + s4.x + s5.x + s6.x + s7.x;
      d1 += s0.y + s1.y + s2.y + s3.y + s4.y + s5.y + s6.y + s7.y;
    }
  }
  for (; p < end; p += 16) {
    int2 q = ab[p];
    float2 s = sc[p];
    float4 ev = EV[(size_t)q.x*16 + sub];
    acc0.x += s.x*ev.x; acc0.y += s.x*ev.y; acc0.z += s.x*ev.z; acc0.w += s.x*ev.w;
    acc1.x += s.y*ev.x; acc1.y += s.y*ev.y; acc1.z += s.y*ev.z; acc1.w += s.y*ev.w;
    if (sub == 0) {
      int oth = q.y & 0xFFFF;
      atomicAdd(&TlB[oth], s.x);
      atomicAdd(&TlB[1000+oth], s.y);
      d0 += s.x; d1 += s.y;
    }
  }
  if (sub == 0) { atomicAdd(&denf[0], d0); atomicAdd(&denf[1], d1); }
  __syncthreads();
  *reinterpret_cast<float4*>(&accRf[slot*64 + sub*4]) = acc0;
  __syncthreads();
  if (t < 64) {
    float s = 0.f;
    #pragma unroll
    for (int sl = 0; sl < 16; ++sl) s += accRf[sl*64 + t];
    accEf[t] = s;
  }
  __syncthreads();
  *reinterpret_cast<float4*>(&accRf[slot*64 + sub*4]) = acc1;
  __syncthreads();
  if (t < 64) {
    float s = 0.f;
    #pragma unroll
    for (int sl = 0; sl < 16; ++sl) s += accRf[sl*64 + t];
    accEf[64 + t] = s;
  }
  __syncthreads();

  // fused post: num = den*Pown + Tl@Poth + accE@a3^T ; write x
  int o = t & 63, part = t >> 6;
  size_t othPOff = side ? 0 : 64000;   // P1 : P2
  size_t ownPOff = side ? 64000 : 0;
  #pragma unroll
  for (int ci = 0; ci < 2; ++ci) {
    int c = side + 2*ci;
    const float* Pc = ws + F_L1 + (size_t)c * 130000;
    const float* Poth = Pc + othPOff;
    float sum = 0.f;
    for (int dd = part*250; dd < part*250 + 250; ++dd)
      sum += TlB[ci*1000 + dd] * Poth[(size_t)dd*64 + o];
    redf[t] = sum;
    __syncthreads();
    if (part == 0) {
      sum = redf[o] + redf[64+o] + redf[128+o] + redf[192+o];
      const float* a = (c==0)?aE0:(c==1)?aT0:(c==2)?aE1:aT1;
      const float* a3 = a + o*192 + 128;
      float acc = 0.f;
      #pragma unroll
      for (int k = 0; k < 64; ++k) acc += accEf[ci*64 + k]*a3[k];
      float den = denf[ci];
      float own = Pc[ownPOff + (size_t)g*64 + o];
      float num = sum + acc + den*own;
      float h = num / (den == 0.f ? 1.f : den);
      float* dst = ws + (side ? F_X2 : F_X1);
      dst[(size_t)g*128 + ci*64 + o] = eluf(h);
    }
    __syncthreads();
  }
}

// ================= out_rel = Rel @ W =================
__global__ void k_relW(const float* Rel, const float* W, float* ws, float* dout) {
  int t = blockIdx.x * blockDim.x + threadIdx.x;
  if (t >= NRELC*128) return;
  int r = t >> 7, o = t & 127;
  const float* x = Rel + (size_t)r*64;
  float s = 0.f;
  #pragma unroll
  for (int k = 0; k < 64; ++k) s += x[k] * W[(size_t)k*128 + o];
  ws[F_OR + t] = s;
  dout[OUT_REL + t] = s;
}

// ================= layer-2 projections: LDS-tiled GEMM + C tail =============
__global__ __launch_bounds__(256) void k_l2_proj(const float* aEo, const float* aTo,
                                                 float* ws) {
  int bid = blockIdx.x;
  int t = threadIdx.x;
  const float* x1 = ws + F_X1;
  const float* x2 = ws + F_X2;
  const float* orel = ws + F_OR;
  if (bid < 278) {
    __shared__ float xs[16][128];
    int c = bid / 139, rem = bid - c*139;
    const float* a = c ? aTo : aEo;
    float* cb = ws + F_L2 + (size_t)c * S2F;
    const float* x; int part, tile, nrows; float* outb;
    if (rem < 63)       { x = x1;   part = 0; tile = rem;       nrows = NT;    outb = cb; }
    else if (rem < 126) { x = x2;   part = 1; tile = rem - 63;  nrows = NT;    outb = cb + 128000; }
    else                { x = orel; part = 2; tile = rem - 126; nrows = NRELC; outb = cb + 256000; }
    int i0 = tile * 16;
    for (int idx = t; idx < 2048; idx += 256) {
      int r = idx >> 7, k = idx & 127;
      int i = i0 + r;
      xs[r][k] = (i < nrows) ? x[(size_t)i*128 + k] : 0.f;
    }
    __syncthreads();
    int o = t & 127, grp = t >> 7;         // 2 groups x 8 rows
    const float* arow = a + (size_t)o*384 + part*128;
    float acc[8] = {0.f,0.f,0.f,0.f,0.f,0.f,0.f,0.f};
    #pragma unroll 4
    for (int k = 0; k < 128; ++k) {
      float av = arow[k];
      #pragma unroll
      for (int r = 0; r < 8; ++r)
        acc[r] += xs[grp*8+r][k] * av;
    }
    int ib = i0 + grp*8;
    #pragma unroll
    for (int r = 0; r < 8; ++r)
      if (ib + r < nrows) outb[(size_t)(ib+r)*128 + o] = acc[r];
  } else {
    int idx = (bid - 278) * 256 + t;       // 4400 = 2 combos x (1000+1000+200)
    if (idx >= 4400) return;
    int c = idx / 2200, rem = idx - c*2200;
    float* base = ws + F_L2 + (size_t)c * S2F;
    if (rem < 1000) {
      const float* u = ws + F_U2 + (size_t)(c*3)*128;
      const float* x = x1 + (size_t)rem*128;
      float s = 0.f;
      for (int k = 0; k < 128; ++k) s += x[k]*u[k];
      base[281600 + rem] = s;
    } else if (rem < 2000) {
      int i = rem - 1000;
      const float* u = ws + F_U2 + (size_t)(c*3+1)*128;
      const float* x = x2 + (size_t)i*128;
      float s = 0.f;
      for (int k = 0; k < 128; ++k) s += x[k]*u[k];
      base[282600 + i] = s;
    } else {
      int r = rem - 2000;
      const float* u = ws + F_U2 + (size_t)(c*3+2)*128;
      const float* x = orel + (size_t)r*128;
      float s = 0.f;
      for (int k = 0; k < 128; ++k) s += x[k]*u[k];
      base[283600 + r] = s;
    }
  }
}

// ================= layer-2 fused pass: 2 segments per block =================
__global__ __launch_bounds__(256) void k_l2_seg(const int* __restrict__ ip,
                                                float* __restrict__ ws,
                                                float* __restrict__ dout) {
  __shared__ float Tl[2][NT];
  __shared__ float Ul[2][NRELC];
  __shared__ float cOthL[NT];
  __shared__ float cRelL[NRELC];
  __shared__ float red[2][256];
  __shared__ float denl[2];

  int c = blockIdx.x >= 500;
  int gp = blockIdx.x - c * 500;
  int g0 = gp * 2;
  int t = threadIdx.x;
  float* base = ws + F_L2 + (size_t)c * S2F;

  size_t othOff = c ? 281600 : 282600;   // C1 : C2
  size_t ownOff = c ? 282600 : 281600;
  for (int i = t; i < NT; i += 256) { Tl[0][i] = 0.f; Tl[1][i] = 0.f; cOthL[i] = base[othOff + i]; }
  for (int i = t; i < NRELC; i += 256) { Ul[0][i] = 0.f; Ul[1][i] = 0.f; cRelL[i] = base[283600 + i]; }
  if (t < 2) denl[t] = 0.f;
  float own0 = base[ownOff + g0];
  float own1 = base[ownOff + g0 + 1];
  __syncthreads();

  const int* st = ip + (c ? I_STARTS_DST : I_STARTS_SRC);
  int s0 = st[g0], split = st[g0 + 1], e1 = st[g0 + 2];
  const int2* ab = reinterpret_cast<const int2*>(ip + (c ? I_AB_DST : I_AB_SRC));

  float d0 = 0.f, d1 = 0.f;
  for (int p = s0 + t; p < e1; p += 256) {
    int2 q = ab[p];
    int oth = q.y & 0xFFFF;
    int r = q.y >> 16;
    int ls = p >= split;
    float sv = scoref((ls ? own1 : own0) + cOthL[oth] + cRelL[r]);
    atomicAdd(&Tl[ls][oth], sv);
    atomicAdd(&Ul[ls][r], sv);
    if (ls) d1 += sv; else d0 += sv;
  }
  atomicAdd(&denl[0], d0);
  atomicAdd(&denl[1], d1);
  __syncthreads();

  int o = t & 127, part = t >> 7;
  const float* Qoth = base + (c ? 0 : 128000);   // Q1 : Q2
  const float* R3 = base + 256000;
  float sum0 = 0.f, sum1 = 0.f;
  for (int dd = part*500; dd < part*500 + 500; ++dd) {
    float qv = Qoth[(size_t)dd*128 + o];
    sum0 += Tl[0][dd] * qv;
    sum1 += Tl[1][dd] * qv;
  }
  for (int rr = part*100; rr < part*100 + 100; ++rr) {
    float qv = R3[(size_t)rr*128 + o];
    sum0 += Ul[0][rr] * qv;
    sum1 += Ul[1][rr] * qv;
  }
  red[0][t] = sum0;
  red[1][t] = sum1;
  __syncthreads();
  int li = part;                 // part 0 -> segment g0, part 1 -> segment g0+1
  float den = denl[li];
  float sum = red[li][o] + red[li][128 + o];
  int gw = g0 + li;
  float ownQ = base[(c ? 128000 : 0) + (size_t)gw*128 + o];
  float num = sum + den * ownQ;
  float h = num / (den == 0.f ? 1.f : den);
  size_t off = c ? (OUT_O2 + (size_t)gw*128 + o) : ((size_t)gw*128 + o);
  dout[off] = eluf(h);
}

extern "C" void kernel_launch(void* const* d_in, const int* in_sizes, int n_in,
                              void* d_out, int out_size, void* d_ws, size_t ws_size,
                              hipStream_t stream) {
  (void)in_sizes; (void)n_in;
  const float* Ent = (const float*)d_in[0];
  const float* Typ = (const float*)d_in[1];
  const float* Rel = (const float*)d_in[2];
  const int*   edge = (const int*)d_in[3];
  const int*   etyp = (const int*)d_in[4];
  const float* Eemb = (const float*)d_in[5];
  const float* aE0 = (const float*)d_in[6];
  const float* vE0 = (const float*)d_in[7];
  const float* aT0 = (const float*)d_in[8];
  const float* vT0 = (const float*)d_in[9];
  const float* aE1 = (const float*)d_in[10];
  const float* vE1 = (const float*)d_in[11];
  const float* aT1 = (const float*)d_in[12];
  const float* vT1 = (const float*)d_in[13];
  const float* aEo = (const float*)d_in[14];
  const float* vEo = (const float*)d_in[15];
  const float* aTo = (const float*)d_in[16];
  const float* vTo = (const float*)d_in[17];
  const float* W   = (const float*)d_in[18];
  float* ws  = (float*)d_ws;
  int*   ip  = (int*)d_ws;
  float* out = (float*)d_out;
  const int* srcA = edge;
  const int* dstA = edge + NE;

  if (ws_size < WS_FLOATS * sizeof(float)) return;

  // zero output (o1 rows >= 1000 stay exactly elu(0)=0); all ws arrays are
  // fully overwritten every call -> no ws memset needed (graph-replay safe)
  hipMemsetAsync(d_out, 0, (size_t)out_size * sizeof(float), stream);

  k_hist2  <<<2*G, 256, 0, stream>>>(srcA, dstA, ip);
  k_colsum <<<8, 256, 0, stream>>>(ip);
  k_scan2b <<<1, 1024, 0, stream>>>(ip);
  k_bases  <<<8, 256, 0, stream>>>(ip);
  k_prep_u <<<6, 256, 0, stream>>>(aE0,vE0,aT0,vT0,aE1,vE1,aT1,vT1,aEo,vEo,aTo,vTo,ws);
  k_l1_proj<<<536, 256, 0, stream>>>(Ent, Typ, aE0, aT0, aE1, aT1, ws);
  k_binscat<<<2*G, 256, 0, stream>>>(Eemb, srcA, dstA, etyp, ip, ws);
  k_l1_acc <<<2000, 256, 0, stream>>>(Eemb, aE0, aT0, aE1, aT1, ip, ws);
  k_relW   <<<100, 256, 0, stream>>>(Rel, W, ws, out);
  k_l2_proj<<<296, 256, 0, stream>>>(aEo, aTo, ws);
  k_l2_seg <<<1000, 256, 0, stream>>>(ip, ws, out);
}

// Round 24
// 251.992 us; speedup vs baseline: 1.2279x; 1.2279x over previous
//
#include <hip/hip_runtime.h>

#define ALPHA 0.2f
#define NT 1000
#define NRELC 200
#define NE 500000
#define N_ENT 100000
#define CH 2048
#define G 245            // ceil(NE/CH)

// ---------------- int workspace layout (int offsets) ----------------
static constexpr size_t I_STARTS_SRC = 0;        // 1001
static constexpr size_t I_STARTS_DST = 1001;     // 1001
static constexpr size_t I_COLSUM     = 2002;     // 2000 [side][bin]
static constexpr size_t I_HIST2      = 4002;     // 2*G*NT = 490000  [side][blk][bin]
static constexpr size_t I_BASE2      = 494002;   // 490000           [side][blk][bin]
static constexpr size_t I_AB_SRC     = 984002;   // 1000000 (500000 int2: j, oth|rel<<16)
static constexpr size_t I_AB_DST     = 1984002;  // 1000000

// ---------------- float workspace layout (float offsets) ----------------
static constexpr size_t F_U1 = 2984004;              // 4 combos x 3 parts x 64
static constexpr size_t F_U2 = F_U1 + 768;           // 2 combos x 3 parts x 128
static constexpr size_t F_L1 = F_U2 + 768;           // 4 combos x 130000
//   per-combo: P1 @0 (1000x64), P2 @64000 (1000x64), C1 @128000 (1000), C2 @129000 (1000)
static constexpr size_t F_X1 = F_L1 + 4*130000;      // 1000x128
static constexpr size_t F_X2 = F_X1 + 128000;        // 1000x128
static constexpr size_t F_OR = F_X2 + 128000;        // 200x128
static constexpr size_t F_L2 = F_OR + 25600;         // 2 combos x 283800
//   per-combo: Q1 @0 (1000x128), Q2 @128000, R3 @256000 (200x128),
//              C1 @281600 (1000), C2 @282600 (1000), C3 @283600 (200)
static constexpr size_t S2F = 283800;
static constexpr size_t WS_FLOATS = F_L2 + 2*S2F;    // ~4.35M floats = 17.4MB

// ---------------- output layout (floats) ----------------
static constexpr size_t OUT_O2  = 12800000;   // 100000*128
static constexpr size_t OUT_REL = 12928000;   // + 200*128

__device__ __forceinline__ float eluf(float x) { return x > 0.f ? x : expm1f(x); }
__device__ __forceinline__ float scoref(float slin) {
  return expf(slin > 0.f ? -slin : -ALPHA * slin);
}

// ================= sort phase 1: per-chunk histograms =================
__global__ __launch_bounds__(256) void k_hist2(const int* __restrict__ src,
                                               const int* __restrict__ dst,
                                               int* __restrict__ ip) {
  __shared__ int h[NT];
  int bid = blockIdx.x;
  int side = bid >= G;
  int blk = bid - side * G;
  const int* keys = side ? dst : src;
  int j0 = blk * CH;
  int n = min(CH, NE - j0);
  for (int i = threadIdx.x; i < NT; i += 256) h[i] = 0;
  __syncthreads();
  for (int k = threadIdx.x; k < n; k += 256) atomicAdd(&h[keys[j0 + k]], 1);
  __syncthreads();
  int* row = ip + I_HIST2 + (size_t)(side * G + blk) * NT;
  for (int b = threadIdx.x; b < NT; b += 256) row[b] = h[b];
}

// ================= sort phase 2a: column sums (parallel) =================
__global__ void k_colsum(int* __restrict__ ip) {
  int t = blockIdx.x * 256 + threadIdx.x;
  if (t >= 2 * NT) return;
  int side = t / NT, bin = t - side * NT;
  int s = 0;
  for (int blk = 0; blk < G; ++blk)
    s += ip[I_HIST2 + (size_t)(side * G + blk) * NT + bin];
  ip[I_COLSUM + t] = s;
}

// ================= sort phase 2b: prefix over 1000 bins =================
__global__ void k_scan2b(int* __restrict__ ip) {
  __shared__ int buf[1024];
  int t = threadIdx.x;
  for (int side = 0; side < 2; ++side) {
    int v = (t < NT) ? ip[I_COLSUM + side * NT + t] : 0;
    buf[t] = v;
    __syncthreads();
    for (int off = 1; off < 1024; off <<= 1) {
      int x = (t >= off) ? buf[t - off] : 0;
      __syncthreads();
      buf[t] += x;
      __syncthreads();
    }
    int* st = ip + (side ? I_STARTS_DST : I_STARTS_SRC);
    if (t < NT) st[t] = buf[t] - v;
    if (t == NT - 1) st[NT] = buf[t];
    __syncthreads();
  }
}

// ================= sort phase 2c: per-(blk,bin) bases (parallel) ========
__global__ void k_bases(int* __restrict__ ip) {
  int t = blockIdx.x * 256 + threadIdx.x;
  if (t >= 2 * NT) return;
  int side = t / NT, bin = t - side * NT;
  int run = ip[(side ? I_STARTS_DST : I_STARTS_SRC) + bin];
  for (int blk = 0; blk < G; ++blk) {
    size_t idx = I_HIST2 + (size_t)(side * G + blk) * NT + bin;
    int c = ip[idx];
    ip[idx + (I_BASE2 - I_HIST2)] = run;
    run += c;
  }
}

// ================= sort phase 3: LDS-binned scatter =================
__global__ __launch_bounds__(256) void k_binscat(const int* __restrict__ src,
                                                 const int* __restrict__ dst,
                                                 const int* __restrict__ et,
                                                 int* __restrict__ ip) {
  __shared__ int2 bufs[CH];
  __shared__ int loff[1024];
  __shared__ int lcur[1024];
  __shared__ int gbase[1024];
  __shared__ int psum[256];
  int bid = blockIdx.x;
  int side = bid >= G;
  int blk = bid - side * G;
  const int* keys = side ? dst : src;
  const int* oths = side ? src : dst;
  int j0 = blk * CH;
  int n = min(CH, NE - j0);
  int t = threadIdx.x;

  for (int i = t; i < 1024; i += 256) lcur[i] = 0;
  __syncthreads();
  for (int k = t; k < n; k += 256) atomicAdd(&lcur[keys[j0 + k]], 1);
  __syncthreads();
  int c0 = lcur[4*t], c1 = lcur[4*t+1], c2 = lcur[4*t+2], c3 = lcur[4*t+3];
  int s = c0 + c1 + c2 + c3;
  psum[t] = s;
  __syncthreads();
  for (int off = 1; off < 256; off <<= 1) {
    int x = (t >= off) ? psum[t - off] : 0;
    __syncthreads();
    psum[t] += x;
    __syncthreads();
  }
  int base = psum[t] - s;
  loff[4*t]   = base;
  loff[4*t+1] = base + c0;
  loff[4*t+2] = base + c0 + c1;
  loff[4*t+3] = base + c0 + c1 + c2;
  lcur[4*t]   = loff[4*t];
  lcur[4*t+1] = loff[4*t+1];
  lcur[4*t+2] = loff[4*t+2];
  lcur[4*t+3] = loff[4*t+3];
  const int* brow = ip + I_BASE2 + (size_t)(side * G + blk) * NT;
  for (int b = t; b < NT; b += 256) gbase[b] = brow[b];
  __syncthreads();
  for (int k = t; k < n; k += 256) {
    int j = j0 + k;
    int b = keys[j];
    int pos = atomicAdd(&lcur[b], 1);
    bufs[pos] = make_int2(j | (b << 19), oths[j] | (et[j] << 16));
  }
  __syncthreads();
  int2* out = reinterpret_cast<int2*>(ip + (side ? I_AB_DST : I_AB_SRC));
  for (int k = t; k < n; k += 256) {
    int2 q = bufs[k];
    int b = q.x >> 19;
    int posg = gbase[b] + (k - loff[b]);
    out[posg] = make_int2(q.x & 0x7FFFF, q.y);
  }
}

// ================= score-factorization u-vectors =================
__global__ void k_prep_u(const float* aE0, const float* vE0, const float* aT0, const float* vT0,
                         const float* aE1, const float* vE1, const float* aT1, const float* vT1,
                         const float* aEo, const float* vEo, const float* aTo, const float* vTo,
                         float* ws) {
  int t = blockIdx.x * blockDim.x + threadIdx.x;
  if (t < 768) {
    int c = t / 192, rem = t - c*192;
    int p = rem >> 6, k = rem & 63;
    const float* a = (c==0)?aE0:(c==1)?aT0:(c==2)?aE1:aT1;
    const float* v = (c==0)?vE0:(c==1)?vT0:(c==2)?vE1:vT1;
    float s = 0.f;
    for (int o = 0; o < 64; ++o) s += a[o*192 + p*64 + k] * v[o];
    ws[F_U1 + (size_t)(c*3+p)*64 + k] = s;
  } else if (t < 1536) {
    int tt = t - 768;
    int c = tt / 384, rem = tt - c*384;
    int p = rem >> 7, k = rem & 127;
    const float* a = c ? aTo : aEo;
    const float* v = c ? vTo : vEo;
    float s = 0.f;
    for (int o = 0; o < 128; ++o) s += a[o*384 + p*128 + k] * v[o];
    ws[F_U2 + (size_t)(c*3+p)*128 + k] = s;
  }
}

// ================= layer-1 projections: LDS-tiled GEMM + C tail =============
__global__ __launch_bounds__(256) void k_l1_proj(const float* Ent, const float* Typ,
                                                 const float* aE0, const float* aT0,
                                                 const float* aE1, const float* aT1,
                                                 float* ws) {
  int bid = blockIdx.x;
  int t = threadIdx.x;
  if (bid < 504) {
    __shared__ float xs[16][64];
    int c = bid / 126, rem = bid - c*126;
    int table = rem / 63, tile = rem - table*63;
    int i0 = tile * 16;
    const float* a = (c==0)?aE0:(c==1)?aT0:(c==2)?aE1:aT1;
    const float* x = table ? Typ : Ent;
    float* outb = ws + F_L1 + (size_t)c*130000 + (table ? 64000 : 0);
    for (int idx = t; idx < 1024; idx += 256) {
      int r = idx >> 6, k = idx & 63;
      int i = i0 + r;
      xs[r][k] = (i < NT) ? x[(size_t)i*64 + k] : 0.f;
    }
    __syncthreads();
    int o = t & 63, grp = t >> 6;          // 4 groups x 4 rows
    const float* arow = a + o*192 + table*64;
    float acc0 = 0.f, acc1 = 0.f, acc2 = 0.f, acc3 = 0.f;
    #pragma unroll 8
    for (int k = 0; k < 64; ++k) {
      float av = arow[k];
      acc0 += xs[grp*4+0][k] * av;
      acc1 += xs[grp*4+1][k] * av;
      acc2 += xs[grp*4+2][k] * av;
      acc3 += xs[grp*4+3][k] * av;
    }
    int ib = i0 + grp*4;
    if (ib + 0 < NT) outb[(size_t)(ib+0)*64 + o] = acc0;
    if (ib + 1 < NT) outb[(size_t)(ib+1)*64 + o] = acc1;
    if (ib + 2 < NT) outb[(size_t)(ib+2)*64 + o] = acc2;
    if (ib + 3 < NT) outb[(size_t)(ib+3)*64 + o] = acc3;
  } else {
    int idx = (bid - 504) * 256 + t;       // 8000 = 4 combos x (C1 1000 + C2 1000)
    if (idx >= 8000) return;
    int c = idx / 2000, rem = idx - c*2000;
    float* base = ws + F_L1 + (size_t)c * 130000;
    if (rem < 1000) {
      const float* x = Ent + (size_t)rem*64;
      const float* u = ws + F_U1 + (size_t)(c*3)*64;
      float s = 0.f;
      #pragma unroll
      for (int k = 0; k < 64; ++k) s += x[k]*u[k];
      base[128000 + rem] = s;
    } else {
      int i = rem - 1000;
      const float* x = Typ + (size_t)i*64;
      const float* u = ws + F_U1 + (size_t)(c*3+1)*64;
      float s = 0.f;
      #pragma unroll
      for (int k = 0; k < 64; ++k) s += x[k]*u[k];
      base[129000 + i] = s;
    }
  }
}

// ================= layer-1 fused: inline scores + accumulate + post ==========
// grid 2000, 256 threads. Manually-carved LDS (17.7KB): accR aliases cOthL.
__global__ __launch_bounds__(256) void k_l1_acc(const float* __restrict__ Eemb,
                                                const float* aE0, const float* aT0,
                                                const float* aE1, const float* aT1,
                                                const int* __restrict__ ip,
                                                float* __restrict__ ws) {
  __shared__ float smem[4434];
  float* TlB   = smem;
  float* cOth0 = smem + 2000;
  float* cOth1 = smem + 3000;
  float* accRf = smem + 2000;
  float* accEf = smem + 4048;
  float* redf  = smem + 4176;
  float* denf  = smem + 4432;

  int side = blockIdx.x >= NT;
  int g = blockIdx.x - side * NT;
  int t = threadIdx.x;
  int sub = t & 15, slot = t >> 4;
  int c0 = side, c1 = side + 2;

  size_t othOff = side ? 128000 : 129000;   // C1 : C2
  size_t ownOff = side ? 129000 : 128000;
  for (int i = t; i < NT; i += 256) {
    TlB[i] = 0.f; TlB[1000 + i] = 0.f;
    cOth0[i] = ws[F_L1 + (size_t)c0*130000 + othOff + i];
    cOth1[i] = ws[F_L1 + (size_t)c1*130000 + othOff + i];
  }
  if (t < 2) denf[t] = 0.f;
  float ownA = ws[F_L1 + (size_t)c0*130000 + ownOff + g];
  float ownB = ws[F_L1 + (size_t)c1*130000 + ownOff + g];
  float4 w3A = reinterpret_cast<const float4*>(ws + F_U1 + (size_t)(c0*3+2)*64)[sub];
  float4 w3B = reinterpret_cast<const float4*>(ws + F_U1 + (size_t)(c1*3+2)*64)[sub];
  __syncthreads();

  int start = ip[(side ? I_STARTS_DST : I_STARTS_SRC) + g];
  int end   = ip[(side ? I_STARTS_DST : I_STARTS_SRC) + g + 1];
  const int2* ab = reinterpret_cast<const int2*>(ip + (side ? I_AB_DST : I_AB_SRC));
  const float4* EV = reinterpret_cast<const float4*>(Eemb);

  float4 acc0 = make_float4(0.f,0.f,0.f,0.f);
  float4 acc1 = make_float4(0.f,0.f,0.f,0.f);
  float d0 = 0.f, d1 = 0.f;

  int p = start + slot;
  for (; p + 48 < end; p += 64) {
    int2 q0 = ab[p], q1 = ab[p+16], q2 = ab[p+32], q3 = ab[p+48];
    float4 e0 = EV[(size_t)q0.x*16 + sub];
    float4 e1 = EV[(size_t)q1.x*16 + sub];
    float4 e2 = EV[(size_t)q2.x*16 + sub];
    float4 e3 = EV[(size_t)q3.x*16 + sub];
    float rA0 = e0.x*w3A.x + e0.y*w3A.y + e0.z*w3A.z + e0.w*w3A.w;
    float rB0 = e0.x*w3B.x + e0.y*w3B.y + e0.z*w3B.z + e0.w*w3B.w;
    float rA1 = e1.x*w3A.x + e1.y*w3A.y + e1.z*w3A.z + e1.w*w3A.w;
    float rB1 = e1.x*w3B.x + e1.y*w3B.y + e1.z*w3B.z + e1.w*w3B.w;
    float rA2 = e2.x*w3A.x + e2.y*w3A.y + e2.z*w3A.z + e2.w*w3A.w;
    float rB2 = e2.x*w3B.x + e2.y*w3B.y + e2.z*w3B.z + e2.w*w3B.w;
    float rA3 = e3.x*w3A.x + e3.y*w3A.y + e3.z*w3A.z + e3.w*w3A.w;
    float rB3 = e3.x*w3B.x + e3.y*w3B.y + e3.z*w3B.z + e3.w*w3B.w;
    #pragma unroll
    for (int sh = 1; sh < 16; sh <<= 1) {
      rA0 += __shfl_xor(rA0, sh, 16); rB0 += __shfl_xor(rB0, sh, 16);
      rA1 += __shfl_xor(rA1, sh, 16); rB1 += __shfl_xor(rB1, sh, 16);
      rA2 += __shfl_xor(rA2, sh, 16); rB2 += __shfl_xor(rB2, sh, 16);
      rA3 += __shfl_xor(rA3, sh, 16); rB3 += __shfl_xor(rB3, sh, 16);
    }
    int o0 = q0.y & 0xFFFF, o1 = q1.y & 0xFFFF, o2 = q2.y & 0xFFFF, o3 = q3.y & 0xFFFF;
    float sA0 = scoref(ownA + cOth0[o0] + rA0);
    float sB0 = scoref(ownB + cOth1[o0] + rB0);
    float sA1 = scoref(ownA + cOth0[o1] + rA1);
    float sB1 = scoref(ownB + cOth1[o1] + rB1);
    float sA2 = scoref(ownA + cOth0[o2] + rA2);
    float sB2 = scoref(ownB + cOth1[o2] + rB2);
    float sA3 = scoref(ownA + cOth0[o3] + rA3);
    float sB3 = scoref(ownB + cOth1[o3] + rB3);
    acc0.x += sA0*e0.x + sA1*e1.x + sA2*e2.x + sA3*e3.x;
    acc0.y += sA0*e0.y + sA1*e1.y + sA2*e2.y + sA3*e3.y;
    acc0.z += sA0*e0.z + sA1*e1.z + sA2*e2.z + sA3*e3.z;
    acc0.w += sA0*e0.w + sA1*e1.w + sA2*e2.w + sA3*e3.w;
    acc1.x += sB0*e0.x + sB1*e1.x + sB2*e2.x + sB3*e3.x;
    acc1.y += sB0*e0.y + sB1*e1.y + sB2*e2.y + sB3*e3.y;
    acc1.z += sB0*e0.z + sB1*e1.z + sB2*e2.z + sB3*e3.z;
    acc1.w += sB0*e0.w + sB1*e1.w + sB2*e2.w + sB3*e3.w;
    if (sub == 0) {
      atomicAdd(&TlB[o0], sA0); atomicAdd(&TlB[1000+o0], sB0);
      atomicAdd(&TlB[o1], sA1); atomicAdd(&TlB[1000+o1], sB1);
      atomicAdd(&TlB[o2], sA2); atomicAdd(&TlB[1000+o2], sB2);
      atomicAdd(&TlB[o3], sA3); atomicAdd(&TlB[1000+o3], sB3);
      d0 += sA0 + sA1 + sA2 + sA3;
      d1 += sB0 + sB1 + sB2 + sB3;
    }
  }
  for (; p < end; p += 16) {
    int2 q = ab[p];
    float4 ev = EV[(size_t)q.x*16 + sub];
    float rA = ev.x*w3A.x + ev.y*w3A.y + ev.z*w3A.z + ev.w*w3A.w;
    float rB = ev.x*w3B.x + ev.y*w3B.y + ev.z*w3B.z + ev.w*w3B.w;
    #pragma unroll
    for (int sh = 1; sh < 16; sh <<= 1) {
      rA += __shfl_xor(rA, sh, 16);
      rB += __shfl_xor(rB, sh, 16);
    }
    int oth = q.y & 0xFFFF;
    float sA = scoref(ownA + cOth0[oth] + rA);
    float sB = scoref(ownB + cOth1[oth] + rB);
    acc0.x += sA*ev.x; acc0.y += sA*ev.y; acc0.z += sA*ev.z; acc0.w += sA*ev.w;
    acc1.x += sB*ev.x; acc1.y += sB*ev.y; acc1.z += sB*ev.z; acc1.w += sB*ev.w;
    if (sub == 0) {
      atomicAdd(&TlB[oth], sA);
      atomicAdd(&TlB[1000+oth], sB);
      d0 += sA; d1 += sB;
    }
  }
  __syncthreads();   // all reads of cOth done before accR aliases it
  *reinterpret_cast<float4*>(&accRf[slot*64 + sub*4])        = acc0;
  *reinterpret_cast<float4*>(&accRf[1024 + slot*64 + sub*4]) = acc1;
  if (sub == 0) { atomicAdd(&denf[0], d0); atomicAdd(&denf[1], d1); }
  __syncthreads();
  if (t < 128) {
    int ci = t >> 6, o = t & 63;
    float s = 0.f;
    #pragma unroll
    for (int sl = 0; sl < 16; ++sl) s += accRf[ci*1024 + sl*64 + o];
    accEf[ci*64 + o] = s;
  }
  __syncthreads();

  // fused post: num = den*Pown + Tl@Poth + accE@a3^T ; write x
  int o = t & 63, part = t >> 6;
  size_t othPOff = side ? 0 : 64000;   // P1 : P2
  size_t ownPOff = side ? 64000 : 0;
  #pragma unroll
  for (int ci = 0; ci < 2; ++ci) {
    int c = side + 2*ci;
    const float* Pc = ws + F_L1 + (size_t)c * 130000;
    const float* Poth = Pc + othPOff;
    float sum = 0.f;
    for (int dd = part*250; dd < part*250 + 250; ++dd)
      sum += TlB[ci*1000 + dd] * Poth[(size_t)dd*64 + o];
    redf[t] = sum;
    __syncthreads();
    if (part == 0) {
      sum = redf[o] + redf[64+o] + redf[128+o] + redf[192+o];
      const float* a = (c==0)?aE0:(c==1)?aT0:(c==2)?aE1:aT1;
      const float* a3 = a + o*192 + 128;
      float acc = 0.f;
      #pragma unroll
      for (int k = 0; k < 64; ++k) acc += accEf[ci*64 + k]*a3[k];
      float den = denf[ci];
      float own = Pc[ownPOff + (size_t)g*64 + o];
      float num = sum + acc + den*own;
      float h = num / (den == 0.f ? 1.f : den);
      float* dst = ws + (side ? F_X2 : F_X1);
      dst[(size_t)g*128 + ci*64 + o] = eluf(h);
    }
    __syncthreads();
  }
}

// ================= out_rel = Rel @ W =================
__global__ void k_relW(const float* Rel, const float* W, float* ws, float* dout) {
  int t = blockIdx.x * blockDim.x + threadIdx.x;
  if (t >= NRELC*128) return;
  int r = t >> 7, o = t & 127;
  const float* x = Rel + (size_t)r*64;
  float s = 0.f;
  #pragma unroll
  for (int k = 0; k < 64; ++k) s += x[k] * W[(size_t)k*128 + o];
  ws[F_OR + t] = s;
  dout[OUT_REL + t] = s;
}

// ================= layer-2 projections: LDS-tiled GEMM + C tail =============
__global__ __launch_bounds__(256) void k_l2_proj(const float* aEo, const float* aTo,
                                                 float* ws) {
  int bid = blockIdx.x;
  int t = threadIdx.x;
  const float* x1 = ws + F_X1;
  const float* x2 = ws + F_X2;
  const float* orel = ws + F_OR;
  if (bid < 278) {
    __shared__ float xs[16][128];
    int c = bid / 139, rem = bid - c*139;
    const float* a = c ? aTo : aEo;
    float* cb = ws + F_L2 + (size_t)c * S2F;
    const float* x; int part, tile, nrows; float* outb;
    if (rem < 63)       { x = x1;   part = 0; tile = rem;       nrows = NT;    outb = cb; }
    else if (rem < 126) { x = x2;   part = 1; tile = rem - 63;  nrows = NT;    outb = cb + 128000; }
    else                { x = orel; part = 2; tile = rem - 126; nrows = NRELC; outb = cb + 256000; }
    int i0 = tile * 16;
    for (int idx = t; idx < 2048; idx += 256) {
      int r = idx >> 7, k = idx & 127;
      int i = i0 + r;
      xs[r][k] = (i < nrows) ? x[(size_t)i*128 + k] : 0.f;
    }
    __syncthreads();
    int o = t & 127, grp = t >> 7;         // 2 groups x 8 rows
    const float* arow = a + (size_t)o*384 + part*128;
    float acc[8] = {0.f,0.f,0.f,0.f,0.f,0.f,0.f,0.f};
    #pragma unroll 4
    for (int k = 0; k < 128; ++k) {
      float av = arow[k];
      #pragma unroll
      for (int r = 0; r < 8; ++r)
        acc[r] += xs[grp*8+r][k] * av;
    }
    int ib = i0 + grp*8;
    #pragma unroll
    for (int r = 0; r < 8; ++r)
      if (ib + r < nrows) outb[(size_t)(ib+r)*128 + o] = acc[r];
  } else {
    int idx = (bid - 278) * 256 + t;       // 4400 = 2 combos x (1000+1000+200)
    if (idx >= 4400) return;
    int c = idx / 2200, rem = idx - c*2200;
    float* base = ws + F_L2 + (size_t)c * S2F;
    if (rem < 1000) {
      const float* u = ws + F_U2 + (size_t)(c*3)*128;
      const float* x = x1 + (size_t)rem*128;
      float s = 0.f;
      for (int k = 0; k < 128; ++k) s += x[k]*u[k];
      base[281600 + rem] = s;
    } else if (rem < 2000) {
      int i = rem - 1000;
      const float* u = ws + F_U2 + (size_t)(c*3+1)*128;
      const float* x = x2 + (size_t)i*128;
      float s = 0.f;
      for (int k = 0; k < 128; ++k) s += x[k]*u[k];
      base[282600 + i] = s;
    } else {
      int r = rem - 2000;
      const float* u = ws + F_U2 + (size_t)(c*3+2)*128;
      const float* x = orel + (size_t)r*128;
      float s = 0.f;
      for (int k = 0; k < 128; ++k) s += x[k]*u[k];
      base[283600 + r] = s;
    }
  }
}

// ================= layer-2 fused pass: 2 segments per block =================
__global__ __launch_bounds__(256) void k_l2_seg(const int* __restrict__ ip,
                                                float* __restrict__ ws,
                                                float* __restrict__ dout) {
  __shared__ float Tl[2][NT];
  __shared__ float Ul[2][NRELC];
  __shared__ float cOthL[NT];
  __shared__ float cRelL[NRELC];
  __shared__ float red[2][256];
  __shared__ float denl[2];

  int c = blockIdx.x >= 500;
  int gp = blockIdx.x - c * 500;
  int g0 = gp * 2;
  int t = threadIdx.x;
  float* base = ws + F_L2 + (size_t)c * S2F;

  size_t othOff = c ? 281600 : 282600;   // C1 : C2
  size_t ownOff = c ? 282600 : 281600;
  for (int i = t; i < NT; i += 256) { Tl[0][i] = 0.f; Tl[1][i] = 0.f; cOthL[i] = base[othOff + i]; }
  for (int i = t; i < NRELC; i += 256) { Ul[0][i] = 0.f; Ul[1][i] = 0.f; cRelL[i] = base[283600 + i]; }
  if (t < 2) denl[t] = 0.f;
  float own0 = base[ownOff + g0];
  float own1 = base[ownOff + g0 + 1];
  __syncthreads();

  const int* st = ip + (c ? I_STARTS_DST : I_STARTS_SRC);
  int s0 = st[g0], split = st[g0 + 1], e1 = st[g0 + 2];
  const int2* ab = reinterpret_cast<const int2*>(ip + (c ? I_AB_DST : I_AB_SRC));

  float d0 = 0.f, d1 = 0.f;
  for (int p = s0 + t; p < e1; p += 256) {
    int2 q = ab[p];
    int oth = q.y & 0xFFFF;
    int r = q.y >> 16;
    int ls = p >= split;
    float sv = scoref((ls ? own1 : own0) + cOthL[oth] + cRelL[r]);
    atomicAdd(&Tl[ls][oth], sv);
    atomicAdd(&Ul[ls][r], sv);
    if (ls) d1 += sv; else d0 += sv;
  }
  atomicAdd(&denl[0], d0);
  atomicAdd(&denl[1], d1);
  __syncthreads();

  int o = t & 127, part = t >> 7;
  const float* Qoth = base + (c ? 0 : 128000);   // Q1 : Q2
  const float* R3 = base + 256000;
  float sum0 = 0.f, sum1 = 0.f;
  for (int dd = part*500; dd < part*500 + 500; ++dd) {
    float qv = Qoth[(size_t)dd*128 + o];
    sum0 += Tl[0][dd] * qv;
    sum1 += Tl[1][dd] * qv;
  }
  for (int rr = part*100; rr < part*100 + 100; ++rr) {
    float qv = R3[(size_t)rr*128 + o];
    sum0 += Ul[0][rr] * qv;
    sum1 += Ul[1][rr] * qv;
  }
  red[0][t] = sum0;
  red[1][t] = sum1;
  __syncthreads();
  int li = part;                 // part 0 -> segment g0, part 1 -> segment g0+1
  float den = denl[li];
  float sum = red[li][o] + red[li][128 + o];
  int gw = g0 + li;
  float ownQ = base[(c ? 128000 : 0) + (size_t)gw*128 + o];
  float num = sum + den * ownQ;
  float h = num / (den == 0.f ? 1.f : den);
  size_t off = c ? (OUT_O2 + (size_t)gw*128 + o) : ((size_t)gw*128 + o);
  dout[off] = eluf(h);
}

extern "C" void kernel_launch(void* const* d_in, const int* in_sizes, int n_in,
                              void* d_out, int out_size, void* d_ws, size_t ws_size,
                              hipStream_t stream) {
  (void)in_sizes; (void)n_in;
  const float* Ent = (const float*)d_in[0];
  const float* Typ = (const float*)d_in[1];
  const float* Rel = (const float*)d_in[2];
  const int*   edge = (const int*)d_in[3];
  const int*   etyp = (const int*)d_in[4];
  const float* Eemb = (const float*)d_in[5];
  const float* aE0 = (const float*)d_in[6];
  const float* vE0 = (const float*)d_in[7];
  const float* aT0 = (const float*)d_in[8];
  const float* vT0 = (const float*)d_in[9];
  const float* aE1 = (const float*)d_in[10];
  const float* vE1 = (const float*)d_in[11];
  const float* aT1 = (const float*)d_in[12];
  const float* vT1 = (const float*)d_in[13];
  const float* aEo = (const float*)d_in[14];
  const float* vEo = (const float*)d_in[15];
  const float* aTo = (const float*)d_in[16];
  const float* vTo = (const float*)d_in[17];
  const float* W   = (const float*)d_in[18];
  float* ws  = (float*)d_ws;
  int*   ip  = (int*)d_ws;
  float* out = (float*)d_out;
  const int* srcA = edge;
  const int* dstA = edge + NE;

  if (ws_size < WS_FLOATS * sizeof(float)) return;

  // zero output (o1 rows >= 1000 stay exactly elu(0)=0); all ws arrays are
  // fully overwritten every call -> no ws memset needed (graph-replay safe)
  hipMemsetAsync(d_out, 0, (size_t)out_size * sizeof(float), stream);

  k_hist2  <<<2*G, 256, 0, stream>>>(srcA, dstA, ip);
  k_colsum <<<8, 256, 0, stream>>>(ip);
  k_scan2b <<<1, 1024, 0, stream>>>(ip);
  k_bases  <<<8, 256, 0, stream>>>(ip);
  k_binscat<<<2*G, 256, 0, stream>>>(srcA, dstA, etyp, ip);
  k_prep_u <<<6, 256, 0, stream>>>(aE0,vE0,aT0,vT0,aE1,vE1,aT1,vT1,aEo,vEo,aTo,vTo,ws);
  k_l1_proj<<<536, 256, 0, stream>>>(Ent, Typ, aE0, aT0, aE1, aT1, ws);
  k_l1_acc <<<2000, 256, 0, stream>>>(Eemb, aE0, aT0, aE1, aT1, ip, ws);
  k_relW   <<<100, 256, 0, stream>>>(Rel, W, ws, out);
  k_l2_proj<<<296, 256, 0, stream>>>(aEo, aTo, ws);
  k_l2_seg <<<1000, 256, 0, stream>>>(ip, ws, out);
}